// Round 1
// baseline (1880.116 us; speedup 1.0000x reference)
//
#include <hip/hip_runtime.h>
#include <hip/hip_bf16.h>
#include <type_traits>

// GroupedQueryAttention: B=2, S=2048, H=2048, NH=32, NKV=8, HD=64, G=4
// Pipeline:
//   1. hs -> bf16
//   2. transpose+cvt weights to [N][K] bf16 (B^T layout for GEMM)
//   3. Q = hs@wq, K = hs@wk, V = hs@wv   (bf16 MFMA GEMM, bf16 out)
//   4. flash attention (fp32 compute, causal), bf16 out
//   5. out = attn@wo (fp32 out)

#define B_SZ 2
#define S_LEN 2048
#define HID 2048
#define NHEADS 32
#define NKVH 8
#define HEADD 64
#define ATT_SCALE 0.125f  // 64^-0.5

typedef __attribute__((ext_vector_type(8))) short bf16x8;
typedef __attribute__((ext_vector_type(4))) float f32x4;

__device__ __forceinline__ float bf2f(unsigned short u) {
  union { unsigned int i; float f; } v;
  v.i = ((unsigned int)u) << 16;
  return v.f;
}
__device__ __forceinline__ unsigned short f2bf(float f) {
  union { float f; unsigned int i; } v;
  v.f = f;
  unsigned int r = v.i + 0x7fffu + ((v.i >> 16) & 1u);
  return (unsigned short)(r >> 16);
}

// ---------------- elementwise f32 -> bf16 ----------------
__global__ void cvt_bf16_kernel(const float4* __restrict__ in,
                                ushort4* __restrict__ out, int n4) {
  int i = blockIdx.x * blockDim.x + threadIdx.x;
  if (i >= n4) return;
  float4 v = in[i];
  ushort4 o;
  o.x = f2bf(v.x); o.y = f2bf(v.y); o.z = f2bf(v.z); o.w = f2bf(v.w);
  out[i] = o;
}

// ---------------- transpose + cvt: in[R][C] f32 -> out[C][R] bf16 ----------------
__global__ void transpose_cvt_kernel(const float* __restrict__ in,
                                     unsigned short* __restrict__ out,
                                     int R, int C) {
  __shared__ float tile[32][33];
  int c0 = blockIdx.x * 32, r0 = blockIdx.y * 32;
  int x = threadIdx.x, y = threadIdx.y;
#pragma unroll
  for (int i = 0; i < 32; i += 8)
    tile[y + i][x] = in[(size_t)(r0 + y + i) * C + c0 + x];
  __syncthreads();
#pragma unroll
  for (int i = 0; i < 32; i += 8)
    out[(size_t)(c0 + y + i) * R + r0 + x] = f2bf(tile[x][y + i]);
}

// ---------------- bf16 MFMA GEMM: C[M][N] = A[M][K] * Bt[N][K]^T ----------------
// 128x128 tile, BK=32, 256 threads = 4 waves (2x2), 4x4 16x16x32 MFMA per wave.
template <typename OutT>
__global__ __launch_bounds__(256) void gemm_bt_kernel(
    const unsigned short* __restrict__ A, const unsigned short* __restrict__ Bt,
    OutT* __restrict__ C, int M, int N, int K) {
  __shared__ unsigned short ldsA[128 * 32];
  __shared__ unsigned short ldsB[128 * 32];
  const int tid = threadIdx.x;
  const int wave = tid >> 6;
  const int lane = tid & 63;
  const int m0 = blockIdx.y * 128;
  const int n0 = blockIdx.x * 128;
  const int wr = wave >> 1, wc = wave & 1;  // 2x2 wave grid, each 64x64
  f32x4 acc[4][4] = {};

  for (int k0 = 0; k0 < K; k0 += 32) {
    __syncthreads();
    // stage A,B tiles: 512 chunks of 16B each; each thread does 2 per matrix
#pragma unroll
    for (int i = 0; i < 2; ++i) {
      int c = tid + i * 256;
      int row = c >> 2;
      int kc = (c & 3) * 8;
      int4 va = *(const int4*)(A + (size_t)(m0 + row) * K + k0 + kc);
      int4 vb = *(const int4*)(Bt + (size_t)(n0 + row) * K + k0 + kc);
      *(int4*)&ldsA[c * 8] = va;
      *(int4*)&ldsB[c * 8] = vb;
    }
    __syncthreads();
    const int kq = (lane >> 4) * 8;
    const int rl = lane & 15;
    bf16x8 a[4], b[4];
#pragma unroll
    for (int mi = 0; mi < 4; ++mi)
      a[mi] = *(const bf16x8*)&ldsA[(wr * 64 + mi * 16 + rl) * 32 + kq];
#pragma unroll
    for (int ni = 0; ni < 4; ++ni)
      b[ni] = *(const bf16x8*)&ldsB[(wc * 64 + ni * 16 + rl) * 32 + kq];
#pragma unroll
    for (int mi = 0; mi < 4; ++mi)
#pragma unroll
      for (int ni = 0; ni < 4; ++ni)
        acc[mi][ni] =
            __builtin_amdgcn_mfma_f32_16x16x32_bf16(a[mi], b[ni], acc[mi][ni], 0, 0, 0);
  }
  // epilogue: C/D layout col=lane&15, row=(lane>>4)*4+reg
#pragma unroll
  for (int mi = 0; mi < 4; ++mi)
#pragma unroll
    for (int ni = 0; ni < 4; ++ni)
#pragma unroll
      for (int r = 0; r < 4; ++r) {
        int row = m0 + wr * 64 + mi * 16 + (lane >> 4) * 4 + r;
        int col = n0 + wc * 64 + ni * 16 + (lane & 15);
        float v = acc[mi][ni][r];
        if constexpr (std::is_same_v<OutT, unsigned short>)
          C[(size_t)row * N + col] = f2bf(v);
        else
          C[(size_t)row * N + col] = v;
      }
}

// ---------------- flash attention (fp32 compute), causal ----------------
// grid: (S/64 q-tiles, NH heads, B). block 256: 64 q-rows x 4 lanes/row.
__global__ __launch_bounds__(256) void flash_attn_kernel(
    const unsigned short* __restrict__ Q, const unsigned short* __restrict__ Kb,
    const unsigned short* __restrict__ Vb, unsigned short* __restrict__ O) {
  __shared__ float Ks[64][64];
  __shared__ float Vs[64][64];
  const int qt = blockIdx.x, head = blockIdx.y, b = blockIdx.z;
  const int kvh = head >> 2;  // G=4
  const int tid = threadIdx.x;
  const int r = tid >> 2, p = tid & 3;  // row in tile, 16-dim slice
  const int s_q = qt * 64 + r;

  float q[16];
  {
    const unsigned short* qp =
        Q + (size_t)(b * S_LEN + s_q) * (NHEADS * HEADD) + head * HEADD + p * 16;
    int4 v0 = *(const int4*)(qp);
    int4 v1 = *(const int4*)(qp + 8);
    const unsigned short* u0 = (const unsigned short*)&v0;
    const unsigned short* u1 = (const unsigned short*)&v1;
#pragma unroll
    for (int i = 0; i < 8; ++i) { q[i] = bf2f(u0[i]); q[8 + i] = bf2f(u1[i]); }
  }
  float m = -INFINITY, l = 0.f;
  float acc[16];
#pragma unroll
  for (int i = 0; i < 16; ++i) acc[i] = 0.f;

  const int kmax = qt * 64 + 63;
  for (int k0 = 0; k0 <= kmax; k0 += 64) {
    __syncthreads();
    {
      // stage K,V tile rows (bf16 -> f32 in LDS); thread t: row r, 16 cols at p*16
      const size_t base =
          (size_t)(b * S_LEN + k0 + r) * (NKVH * HEADD) + kvh * HEADD + p * 16;
      int4 kv0 = *(const int4*)(Kb + base);
      int4 kv1 = *(const int4*)(Kb + base + 8);
      int4 vv0 = *(const int4*)(Vb + base);
      int4 vv1 = *(const int4*)(Vb + base + 8);
      const unsigned short* ka = (const unsigned short*)&kv0;
      const unsigned short* kb2 = (const unsigned short*)&kv1;
      const unsigned short* va = (const unsigned short*)&vv0;
      const unsigned short* vb2 = (const unsigned short*)&vv1;
      float4 f;
      f.x = bf2f(ka[0]); f.y = bf2f(ka[1]); f.z = bf2f(ka[2]); f.w = bf2f(ka[3]);
      *(float4*)&Ks[r][p * 16 + 0] = f;
      f.x = bf2f(ka[4]); f.y = bf2f(ka[5]); f.z = bf2f(ka[6]); f.w = bf2f(ka[7]);
      *(float4*)&Ks[r][p * 16 + 4] = f;
      f.x = bf2f(kb2[0]); f.y = bf2f(kb2[1]); f.z = bf2f(kb2[2]); f.w = bf2f(kb2[3]);
      *(float4*)&Ks[r][p * 16 + 8] = f;
      f.x = bf2f(kb2[4]); f.y = bf2f(kb2[5]); f.z = bf2f(kb2[6]); f.w = bf2f(kb2[7]);
      *(float4*)&Ks[r][p * 16 + 12] = f;
      f.x = bf2f(va[0]); f.y = bf2f(va[1]); f.z = bf2f(va[2]); f.w = bf2f(va[3]);
      *(float4*)&Vs[r][p * 16 + 0] = f;
      f.x = bf2f(va[4]); f.y = bf2f(va[5]); f.z = bf2f(va[6]); f.w = bf2f(va[7]);
      *(float4*)&Vs[r][p * 16 + 4] = f;
      f.x = bf2f(vb2[0]); f.y = bf2f(vb2[1]); f.z = bf2f(vb2[2]); f.w = bf2f(vb2[3]);
      *(float4*)&Vs[r][p * 16 + 8] = f;
      f.x = bf2f(vb2[4]); f.y = bf2f(vb2[5]); f.z = bf2f(vb2[6]); f.w = bf2f(vb2[7]);
      *(float4*)&Vs[r][p * 16 + 12] = f;
    }
    __syncthreads();
    for (int j = 0; j < 64; ++j) {
      int kk = k0 + j;
      if (kk > s_q) break;  // causal; partner lanes (same row) break together
      float s = 0.f;
      const float* kj = &Ks[j][p * 16];
#pragma unroll
      for (int i = 0; i < 16; ++i) s += q[i] * kj[i];
      s += __shfl_xor(s, 1);
      s += __shfl_xor(s, 2);
      s *= ATT_SCALE;
      if (s > m) {
        float alpha = __expf(m - s);
        l *= alpha;
#pragma unroll
        for (int i = 0; i < 16; ++i) acc[i] *= alpha;
        m = s;
      }
      float pw = __expf(s - m);
      l += pw;
      const float* vj = &Vs[j][p * 16];
#pragma unroll
      for (int i = 0; i < 16; ++i) acc[i] += pw * vj[i];
    }
  }
  float inv = 1.0f / l;
  union { int4 v[2]; unsigned short u[16]; } ou;
#pragma unroll
  for (int i = 0; i < 16; ++i) ou.u[i] = f2bf(acc[i] * inv);
  unsigned short* op =
      O + (size_t)(b * S_LEN + s_q) * (NHEADS * HEADD) + head * HEADD + p * 16;
  *(int4*)(op) = ou.v[0];
  *(int4*)(op + 8) = ou.v[1];
}

extern "C" void kernel_launch(void* const* d_in, const int* in_sizes, int n_in,
                              void* d_out, int out_size, void* d_ws, size_t ws_size,
                              hipStream_t stream) {
  const float* hs = (const float*)d_in[0];
  // d_in[1] = attention_mask: guaranteed causal; implemented analytically
  const float* wq = (const float*)d_in[2];
  const float* wk = (const float*)d_in[3];
  const float* wv = (const float*)d_in[4];
  const float* wo = (const float*)d_in[5];
  float* out = (float*)d_out;

  char* ws = (char*)d_ws;
  unsigned short* hs_bf = (unsigned short*)(ws);                        // 16 MB
  unsigned short* wqT = (unsigned short*)(ws + ((size_t)16 << 20));     // 8 MB
  unsigned short* wkT = (unsigned short*)(ws + ((size_t)24 << 20));     // 2 MB
  unsigned short* wvT = (unsigned short*)(ws + ((size_t)26 << 20));     // 2 MB
  unsigned short* woT = (unsigned short*)(ws + ((size_t)28 << 20));     // 8 MB
  unsigned short* Qb  = (unsigned short*)(ws + ((size_t)36 << 20));     // 16 MB
  unsigned short* Kb  = (unsigned short*)(ws + ((size_t)52 << 20));     // 4 MB
  unsigned short* Vb  = (unsigned short*)(ws + ((size_t)56 << 20));     // 4 MB
  unsigned short* Ab  = (unsigned short*)(ws + ((size_t)60 << 20));     // 16 MB

  // 1. hs -> bf16
  int n4 = (B_SZ * S_LEN * HID) / 4;
  cvt_bf16_kernel<<<n4 / 256, 256, 0, stream>>>((const float4*)hs, (ushort4*)hs_bf, n4);

  // 2. weight transposes ([K][N] f32 -> [N][K] bf16)
  dim3 tb(32, 8);
  transpose_cvt_kernel<<<dim3(64, 64), tb, 0, stream>>>(wq, wqT, HID, NHEADS * HEADD);
  transpose_cvt_kernel<<<dim3(16, 64), tb, 0, stream>>>(wk, wkT, HID, NKVH * HEADD);
  transpose_cvt_kernel<<<dim3(16, 64), tb, 0, stream>>>(wv, wvT, HID, NKVH * HEADD);
  transpose_cvt_kernel<<<dim3(64, 64), tb, 0, stream>>>(wo, woT, NHEADS * HEADD, HID);

  // 3. projections
  gemm_bt_kernel<unsigned short><<<dim3(16, 32), 256, 0, stream>>>(
      hs_bf, wqT, Qb, B_SZ * S_LEN, NHEADS * HEADD, HID);
  gemm_bt_kernel<unsigned short><<<dim3(4, 32), 256, 0, stream>>>(
      hs_bf, wkT, Kb, B_SZ * S_LEN, NKVH * HEADD, HID);
  gemm_bt_kernel<unsigned short><<<dim3(4, 32), 256, 0, stream>>>(
      hs_bf, wvT, Vb, B_SZ * S_LEN, NKVH * HEADD, HID);

  // 4. attention
  flash_attn_kernel<<<dim3(S_LEN / 64, NHEADS, B_SZ), 256, 0, stream>>>(Qb, Kb, Vb, Ab);

  // 5. output projection (fp32 out)
  gemm_bt_kernel<float><<<dim3(16, 32), 256, 0, stream>>>(
      Ab, woT, out, B_SZ * S_LEN, HID, HID);
}

// Round 2
// 473.682 us; speedup vs baseline: 3.9692x; 3.9692x over previous
//
#include <hip/hip_runtime.h>
#include <hip/hip_bf16.h>
#include <type_traits>

// GroupedQueryAttention: B=2, S=2048, H=2048, NH=32, NKV=8, HD=64, G=4
// Pipeline:
//   1. hs -> bf16
//   2. transpose+cvt weights to [N][K] bf16 (B^T layout for GEMM)
//   3. Q = hs@wq, K = hs@wk, V = hs@wv   (bf16 MFMA GEMM, bf16 out)
//   3b. V -> V^T  ([b][kvh][d][s]) for MFMA PV step
//   4. MFMA flash attention (fp32 softmax, causal), bf16 out
//   5. out = attn@wo (fp32 out)

#define B_SZ 2
#define S_LEN 2048
#define HID 2048
#define NHEADS 32
#define NKVH 8
#define HEADD 64
#define ATT_SCALE 0.125f  // 64^-0.5

typedef __attribute__((ext_vector_type(8))) short bf16x8;
typedef __attribute__((ext_vector_type(4))) float f32x4;

__device__ __forceinline__ float bf2f(unsigned short u) {
  union { unsigned int i; float f; } v;
  v.i = ((unsigned int)u) << 16;
  return v.f;
}
__device__ __forceinline__ unsigned short f2bf(float f) {
  union { float f; unsigned int i; } v;
  v.f = f;
  unsigned int r = v.i + 0x7fffu + ((v.i >> 16) & 1u);
  return (unsigned short)(r >> 16);
}

// ---------------- elementwise f32 -> bf16 ----------------
__global__ void cvt_bf16_kernel(const float4* __restrict__ in,
                                ushort4* __restrict__ out, int n4) {
  int i = blockIdx.x * blockDim.x + threadIdx.x;
  if (i >= n4) return;
  float4 v = in[i];
  ushort4 o;
  o.x = f2bf(v.x); o.y = f2bf(v.y); o.z = f2bf(v.z); o.w = f2bf(v.w);
  out[i] = o;
}

// ---------------- transpose + cvt: in[R][C] f32 -> out[C][R] bf16 ----------------
__global__ void transpose_cvt_kernel(const float* __restrict__ in,
                                     unsigned short* __restrict__ out,
                                     int R, int C) {
  __shared__ float tile[32][33];
  int c0 = blockIdx.x * 32, r0 = blockIdx.y * 32;
  int x = threadIdx.x, y = threadIdx.y;
#pragma unroll
  for (int i = 0; i < 32; i += 8)
    tile[y + i][x] = in[(size_t)(r0 + y + i) * C + c0 + x];
  __syncthreads();
#pragma unroll
  for (int i = 0; i < 32; i += 8)
    out[(size_t)(c0 + y + i) * R + r0 + x] = f2bf(tile[x][y + i]);
}

// ---------------- bf16 transpose: V[b,s,kvh*64+d] -> Vt[(b*8+kvh)*64+d][s] ----
__global__ void transpose_v_kernel(const unsigned short* __restrict__ V,
                                   unsigned short* __restrict__ Vt) {
  __shared__ unsigned short tile[32][33];
  int s0 = blockIdx.x * 32, d0 = blockIdx.y * 32;
  int bk = blockIdx.z;
  int b = bk >> 3, kvh = bk & 7;
  int x = threadIdx.x, y = threadIdx.y;
#pragma unroll
  for (int i = 0; i < 32; i += 8)
    tile[y + i][x] =
        V[(size_t)(b * S_LEN + s0 + y + i) * (NKVH * HEADD) + kvh * HEADD + d0 + x];
  __syncthreads();
#pragma unroll
  for (int i = 0; i < 32; i += 8)
    Vt[((size_t)(b * NKVH + kvh) * HEADD + d0 + y + i) * S_LEN + s0 + x] =
        tile[x][y + i];
}

// ---------------- bf16 MFMA GEMM: C[M][N] = A[M][K] * Bt[N][K]^T ----------------
template <typename OutT>
__global__ __launch_bounds__(256) void gemm_bt_kernel(
    const unsigned short* __restrict__ A, const unsigned short* __restrict__ Bt,
    OutT* __restrict__ C, int M, int N, int K) {
  __shared__ unsigned short ldsA[128 * 32];
  __shared__ unsigned short ldsB[128 * 32];
  const int tid = threadIdx.x;
  const int wave = tid >> 6;
  const int lane = tid & 63;
  const int m0 = blockIdx.y * 128;
  const int n0 = blockIdx.x * 128;
  const int wr = wave >> 1, wc = wave & 1;
  f32x4 acc[4][4] = {};

  for (int k0 = 0; k0 < K; k0 += 32) {
    __syncthreads();
#pragma unroll
    for (int i = 0; i < 2; ++i) {
      int c = tid + i * 256;
      int row = c >> 2;
      int kc = (c & 3) * 8;
      int4 va = *(const int4*)(A + (size_t)(m0 + row) * K + k0 + kc);
      int4 vb = *(const int4*)(Bt + (size_t)(n0 + row) * K + k0 + kc);
      *(int4*)&ldsA[c * 8] = va;
      *(int4*)&ldsB[c * 8] = vb;
    }
    __syncthreads();
    const int kq = (lane >> 4) * 8;
    const int rl = lane & 15;
    bf16x8 a[4], b[4];
#pragma unroll
    for (int mi = 0; mi < 4; ++mi)
      a[mi] = *(const bf16x8*)&ldsA[(wr * 64 + mi * 16 + rl) * 32 + kq];
#pragma unroll
    for (int ni = 0; ni < 4; ++ni)
      b[ni] = *(const bf16x8*)&ldsB[(wc * 64 + ni * 16 + rl) * 32 + kq];
#pragma unroll
    for (int mi = 0; mi < 4; ++mi)
#pragma unroll
      for (int ni = 0; ni < 4; ++ni)
        acc[mi][ni] =
            __builtin_amdgcn_mfma_f32_16x16x32_bf16(a[mi], b[ni], acc[mi][ni], 0, 0, 0);
  }
#pragma unroll
  for (int mi = 0; mi < 4; ++mi)
#pragma unroll
    for (int ni = 0; ni < 4; ++ni)
#pragma unroll
      for (int r = 0; r < 4; ++r) {
        int row = m0 + wr * 64 + mi * 16 + (lane >> 4) * 4 + r;
        int col = n0 + wc * 64 + ni * 16 + (lane & 15);
        float v = acc[mi][ni][r];
        if constexpr (std::is_same_v<OutT, unsigned short>)
          C[(size_t)row * N + col] = f2bf(v);
        else
          C[(size_t)row * N + col] = v;
      }
}

// ---------------- MFMA flash attention ----------------
// grid: (S/64, NH, B). block 256 = 4 waves; wave w owns q rows [qt*64+w*16, +16).
// KV tile = 64. LDS: Ks[64][64] (XOR-swz), Vs=V^T[64 d][64 kv] (XOR-swz),
// Pl per-wave [16 q][64 kv] (XOR-swz). All MFMA operand reads are ds_read_b128.
__global__ __launch_bounds__(256) void mfma_attn_kernel(
    const unsigned short* __restrict__ Q,   // [B*S][NH*64]
    const unsigned short* __restrict__ Kb,  // [B*S][NKV*64]
    const unsigned short* __restrict__ Vt,  // [(b*8+kvh)*64+d][S]
    unsigned short* __restrict__ O) {       // [B*S][NH*64]
  __shared__ unsigned short Ks[64 * 64];
  __shared__ unsigned short Vs[64 * 64];
  __shared__ unsigned short Pl[4 * 16 * 64];
  const int qt = blockIdx.x, head = blockIdx.y, b = blockIdx.z;
  const int kvh = head >> 2;
  const int tid = threadIdx.x;
  const int w = tid >> 6, lane = tid & 63;
  const int c = lane & 15, g = lane >> 4;
  unsigned short* Plw = Pl + w * 1024;

  // Q fragment (A-operand): row = c, k(d) = ks*32 + g*8 + [0..8)
  bf16x8 qf[2];
  {
    const unsigned short* qp =
        Q + (size_t)(b * S_LEN + qt * 64 + w * 16 + c) * (NHEADS * HEADD) +
        head * HEADD + g * 8;
    qf[0] = *(const bf16x8*)(qp);
    qf[1] = *(const bf16x8*)(qp + 32);
  }
  f32x4 o_acc[4] = {};  // dn blocks; lane holds rows g*4+r, col dn*16+c
  float mstate[4], lstate[4];
#pragma unroll
  for (int r = 0; r < 4; ++r) { mstate[r] = -INFINITY; lstate[r] = 0.f; }

  const int ntiles = qt + 1;
  for (int t = 0; t < ntiles; ++t) {
    const int kv0 = t * 64;
    __syncthreads();
    // stage K tile (row-major [kv][d], swz) and V^T tile ([d][kv], swz)
#pragma unroll
    for (int i = 0; i < 2; ++i) {
      int cc = tid + i * 256;
      int row = cc >> 3, slot = cc & 7;
      int4 kvv = *(const int4*)(Kb + (size_t)(b * S_LEN + kv0 + row) * (NKVH * HEADD) +
                                kvh * HEADD + slot * 8);
      *(int4*)&Ks[row * 64 + ((slot ^ (row & 7)) * 8)] = kvv;
      int4 vvv = *(const int4*)(Vt + ((size_t)(b * NKVH + kvh) * HEADD + row) * S_LEN +
                                kv0 + slot * 8);
      *(int4*)&Vs[row * 64 + ((slot ^ (row & 7)) * 8)] = vvv;
    }
    __syncthreads();
    // ---- QK^T: S[16 q][64 kv] per wave ----
    f32x4 s_acc[4] = {};
#pragma unroll
    for (int ks = 0; ks < 2; ++ks)
#pragma unroll
      for (int kn = 0; kn < 4; ++kn) {
        bf16x8 bf =
            *(const bf16x8*)&Ks[(kn * 16 + c) * 64 + (((ks * 4 + g) ^ (c & 7)) * 8)];
        s_acc[kn] = __builtin_amdgcn_mfma_f32_16x16x32_bf16(qf[ks], bf, s_acc[kn], 0, 0, 0);
      }
    // ---- scale + causal mask ----
    float s[4][4];
#pragma unroll
    for (int kn = 0; kn < 4; ++kn)
#pragma unroll
      for (int r = 0; r < 4; ++r) s[kn][r] = s_acc[kn][r] * ATT_SCALE;
    if (t == qt) {
#pragma unroll
      for (int kn = 0; kn < 4; ++kn)
#pragma unroll
        for (int r = 0; r < 4; ++r)
          if (kv0 + kn * 16 + c > qt * 64 + w * 16 + g * 4 + r) s[kn][r] = -1e30f;
    }
    // ---- online softmax: row max ----
    float mx[4];
#pragma unroll
    for (int r = 0; r < 4; ++r)
      mx[r] = fmaxf(fmaxf(s[0][r], s[1][r]), fmaxf(s[2][r], s[3][r]));
#pragma unroll
    for (int r = 0; r < 4; ++r) {
      mx[r] = fmaxf(mx[r], __shfl_xor(mx[r], 1));
      mx[r] = fmaxf(mx[r], __shfl_xor(mx[r], 2));
      mx[r] = fmaxf(mx[r], __shfl_xor(mx[r], 4));
      mx[r] = fmaxf(mx[r], __shfl_xor(mx[r], 8));
    }
    float alpha[4];
#pragma unroll
    for (int r = 0; r < 4; ++r) {
      float nm = fmaxf(mstate[r], mx[r]);
      alpha[r] = __expf(mstate[r] - nm);
      mstate[r] = nm;
    }
    // ---- P = exp(s - m) -> bf16 -> per-wave LDS (swz); row sums ----
    float rsum[4] = {0.f, 0.f, 0.f, 0.f};
#pragma unroll
    for (int kn = 0; kn < 4; ++kn)
#pragma unroll
      for (int r = 0; r < 4; ++r) {
        float p = __expf(s[kn][r] - mstate[r]);
        unsigned short pb = f2bf(p);
        rsum[r] += bf2f(pb);
        int q = g * 4 + r, k = kn * 16 + c;
        Plw[q * 64 + (k ^ ((q & 7) << 3))] = pb;
      }
#pragma unroll
    for (int r = 0; r < 4; ++r) {
      rsum[r] += __shfl_xor(rsum[r], 1);
      rsum[r] += __shfl_xor(rsum[r], 2);
      rsum[r] += __shfl_xor(rsum[r], 4);
      rsum[r] += __shfl_xor(rsum[r], 8);
      lstate[r] = lstate[r] * alpha[r] + rsum[r];
    }
#pragma unroll
    for (int dn = 0; dn < 4; ++dn)
#pragma unroll
      for (int r = 0; r < 4; ++r) o_acc[dn][r] *= alpha[r];
    // ---- PV: O[16 q][64 d] += P[16][64] @ V[64][64] ----
    bf16x8 af[2];
#pragma unroll
    for (int ks2 = 0; ks2 < 2; ++ks2)
      af[ks2] = *(const bf16x8*)&Plw[c * 64 + ((ks2 * 32 + g * 8) ^ ((c & 7) << 3))];
#pragma unroll
    for (int ks2 = 0; ks2 < 2; ++ks2)
#pragma unroll
      for (int dn = 0; dn < 4; ++dn) {
        bf16x8 vf =
            *(const bf16x8*)&Vs[(dn * 16 + c) * 64 + (((ks2 * 4 + g) ^ (c & 7)) * 8)];
        o_acc[dn] = __builtin_amdgcn_mfma_f32_16x16x32_bf16(af[ks2], vf, o_acc[dn], 0, 0, 0);
      }
  }
  // ---- epilogue: O = o_acc / l ----
  float inv[4];
#pragma unroll
  for (int r = 0; r < 4; ++r) inv[r] = 1.0f / lstate[r];
#pragma unroll
  for (int dn = 0; dn < 4; ++dn)
#pragma unroll
    for (int r = 0; r < 4; ++r) {
      int row = qt * 64 + w * 16 + g * 4 + r;
      int col = head * HEADD + dn * 16 + c;
      O[(size_t)(b * S_LEN + row) * (NHEADS * HEADD) + col] = f2bf(o_acc[dn][r] * inv[r]);
    }
}

extern "C" void kernel_launch(void* const* d_in, const int* in_sizes, int n_in,
                              void* d_out, int out_size, void* d_ws, size_t ws_size,
                              hipStream_t stream) {
  const float* hs = (const float*)d_in[0];
  // d_in[1] = attention_mask: guaranteed causal; implemented analytically
  const float* wq = (const float*)d_in[2];
  const float* wk = (const float*)d_in[3];
  const float* wv = (const float*)d_in[4];
  const float* wo = (const float*)d_in[5];
  float* out = (float*)d_out;

  char* ws = (char*)d_ws;
  unsigned short* hs_bf = (unsigned short*)(ws);                        // 16 MB
  unsigned short* wqT = (unsigned short*)(ws + ((size_t)16 << 20));     // 8 MB
  unsigned short* wkT = (unsigned short*)(ws + ((size_t)24 << 20));     // 2 MB
  unsigned short* wvT = (unsigned short*)(ws + ((size_t)26 << 20));     // 2 MB
  unsigned short* woT = (unsigned short*)(ws + ((size_t)28 << 20));     // 8 MB
  unsigned short* Qb  = (unsigned short*)(ws + ((size_t)36 << 20));     // 16 MB
  unsigned short* Kb  = (unsigned short*)(ws + ((size_t)52 << 20));     // 4 MB
  unsigned short* Vb  = (unsigned short*)(ws + ((size_t)56 << 20));     // 4 MB
  unsigned short* Ab  = (unsigned short*)(ws + ((size_t)60 << 20));     // 16 MB
  unsigned short* VtB = (unsigned short*)(ws + ((size_t)76 << 20));     // 4 MB

  // 1. hs -> bf16
  int n4 = (B_SZ * S_LEN * HID) / 4;
  cvt_bf16_kernel<<<n4 / 256, 256, 0, stream>>>((const float4*)hs, (ushort4*)hs_bf, n4);

  // 2. weight transposes ([K][N] f32 -> [N][K] bf16)
  dim3 tb(32, 8);
  transpose_cvt_kernel<<<dim3(64, 64), tb, 0, stream>>>(wq, wqT, HID, NHEADS * HEADD);
  transpose_cvt_kernel<<<dim3(16, 64), tb, 0, stream>>>(wk, wkT, HID, NKVH * HEADD);
  transpose_cvt_kernel<<<dim3(16, 64), tb, 0, stream>>>(wv, wvT, HID, NKVH * HEADD);
  transpose_cvt_kernel<<<dim3(64, 64), tb, 0, stream>>>(wo, woT, NHEADS * HEADD, HID);

  // 3. projections
  gemm_bt_kernel<unsigned short><<<dim3(16, 32), 256, 0, stream>>>(
      hs_bf, wqT, Qb, B_SZ * S_LEN, NHEADS * HEADD, HID);
  gemm_bt_kernel<unsigned short><<<dim3(4, 32), 256, 0, stream>>>(
      hs_bf, wkT, Kb, B_SZ * S_LEN, NKVH * HEADD, HID);
  gemm_bt_kernel<unsigned short><<<dim3(4, 32), 256, 0, stream>>>(
      hs_bf, wvT, Vb, B_SZ * S_LEN, NKVH * HEADD, HID);

  // 3b. V -> V^T
  transpose_v_kernel<<<dim3(S_LEN / 32, HEADD / 32, B_SZ * NKVH), tb, 0, stream>>>(
      Vb, VtB);

  // 4. attention (MFMA flash)
  mfma_attn_kernel<<<dim3(S_LEN / 64, NHEADS, B_SZ), 256, 0, stream>>>(Qb, Kb, VtB, Ab);

  // 5. output projection (fp32 out)
  gemm_bt_kernel<float><<<dim3(16, 32), 256, 0, stream>>>(
      Ab, woT, out, B_SZ * S_LEN, HID, HID);
}

// Round 3
// 350.653 us; speedup vs baseline: 5.3618x; 1.3509x over previous
//
#include <hip/hip_runtime.h>
#include <hip/hip_bf16.h>
#include <type_traits>

// GroupedQueryAttention: B=2, S=2048, H=2048, NH=32, NKV=8, HD=64, G=4
// Pipeline:
//   1. hs -> bf16
//   2. transpose+cvt weights to [N][K] bf16 (B^T layout for GEMM)
//   3. Q = hs@wq (N=2048), KV = hs@[wk|wv] (N=1024, merged)
//   3b. V -> V^T  ([b][kvh][d][s]) for MFMA PV step
//   4. MFMA flash attention: causal-paired q-tiles, double-buffered K/V
//   5. out = attn@wo (fp32 out)

#define B_SZ 2
#define S_LEN 2048
#define HID 2048
#define NHEADS 32
#define NKVH 8
#define HEADD 64
#define ATT_SCALE 0.125f  // 64^-0.5

typedef __attribute__((ext_vector_type(8))) short bf16x8;
typedef __attribute__((ext_vector_type(4))) float f32x4;

__device__ __forceinline__ float bf2f(unsigned short u) {
  union { unsigned int i; float f; } v;
  v.i = ((unsigned int)u) << 16;
  return v.f;
}
__device__ __forceinline__ unsigned short f2bf(float f) {
  union { float f; unsigned int i; } v;
  v.f = f;
  unsigned int r = v.i + 0x7fffu + ((v.i >> 16) & 1u);
  return (unsigned short)(r >> 16);
}

// ---------------- elementwise f32 -> bf16 ----------------
__global__ void cvt_bf16_kernel(const float4* __restrict__ in,
                                ushort4* __restrict__ out, int n4) {
  int i = blockIdx.x * blockDim.x + threadIdx.x;
  if (i >= n4) return;
  float4 v = in[i];
  ushort4 o;
  o.x = f2bf(v.x); o.y = f2bf(v.y); o.z = f2bf(v.z); o.w = f2bf(v.w);
  out[i] = o;
}

// ---------------- transpose + cvt: in[R][C] f32 -> out[C][R] bf16 ----------------
__global__ void transpose_cvt_kernel(const float* __restrict__ in,
                                     unsigned short* __restrict__ out,
                                     int R, int C) {
  __shared__ float tile[32][33];
  int c0 = blockIdx.x * 32, r0 = blockIdx.y * 32;
  int x = threadIdx.x, y = threadIdx.y;
#pragma unroll
  for (int i = 0; i < 32; i += 8)
    tile[y + i][x] = in[(size_t)(r0 + y + i) * C + c0 + x];
  __syncthreads();
#pragma unroll
  for (int i = 0; i < 32; i += 8)
    out[(size_t)(c0 + y + i) * R + r0 + x] = f2bf(tile[x][y + i]);
}

// ---------------- bf16 transpose: KV[b,s,512+kvh*64+d] -> Vt[(b*8+kvh)*64+d][s] ----
__global__ void transpose_v_kernel(const unsigned short* __restrict__ KVb,
                                   unsigned short* __restrict__ Vt) {
  __shared__ unsigned short tile[32][33];
  int s0 = blockIdx.x * 32, d0 = blockIdx.y * 32;
  int bk = blockIdx.z;
  int b = bk >> 3, kvh = bk & 7;
  int x = threadIdx.x, y = threadIdx.y;
#pragma unroll
  for (int i = 0; i < 32; i += 8)
    tile[y + i][x] =
        KVb[(size_t)(b * S_LEN + s0 + y + i) * 1024 + 512 + kvh * HEADD + d0 + x];
  __syncthreads();
#pragma unroll
  for (int i = 0; i < 32; i += 8)
    Vt[((size_t)(b * NKVH + kvh) * HEADD + d0 + y + i) * S_LEN + s0 + x] =
        tile[x][y + i];
}

// ---------------- bf16 MFMA GEMM: C[M][N] = A[M][K] * Bt[N][K]^T ----------------
template <typename OutT>
__global__ __launch_bounds__(256) void gemm_bt_kernel(
    const unsigned short* __restrict__ A, const unsigned short* __restrict__ Bt,
    OutT* __restrict__ C, int M, int N, int K) {
  __shared__ unsigned short ldsA[128 * 32];
  __shared__ unsigned short ldsB[128 * 32];
  const int tid = threadIdx.x;
  const int wave = tid >> 6;
  const int lane = tid & 63;
  const int m0 = blockIdx.y * 128;
  const int n0 = blockIdx.x * 128;
  const int wr = wave >> 1, wc = wave & 1;
  f32x4 acc[4][4] = {};

  for (int k0 = 0; k0 < K; k0 += 32) {
    __syncthreads();
#pragma unroll
    for (int i = 0; i < 2; ++i) {
      int c = tid + i * 256;
      int row = c >> 2;
      int kc = (c & 3) * 8;
      int4 va = *(const int4*)(A + (size_t)(m0 + row) * K + k0 + kc);
      int4 vb = *(const int4*)(Bt + (size_t)(n0 + row) * K + k0 + kc);
      *(int4*)&ldsA[c * 8] = va;
      *(int4*)&ldsB[c * 8] = vb;
    }
    __syncthreads();
    const int kq = (lane >> 4) * 8;
    const int rl = lane & 15;
    bf16x8 a[4], b[4];
#pragma unroll
    for (int mi = 0; mi < 4; ++mi)
      a[mi] = *(const bf16x8*)&ldsA[(wr * 64 + mi * 16 + rl) * 32 + kq];
#pragma unroll
    for (int ni = 0; ni < 4; ++ni)
      b[ni] = *(const bf16x8*)&ldsB[(wc * 64 + ni * 16 + rl) * 32 + kq];
#pragma unroll
    for (int mi = 0; mi < 4; ++mi)
#pragma unroll
      for (int ni = 0; ni < 4; ++ni)
        acc[mi][ni] =
            __builtin_amdgcn_mfma_f32_16x16x32_bf16(a[mi], b[ni], acc[mi][ni], 0, 0, 0);
  }
#pragma unroll
  for (int mi = 0; mi < 4; ++mi)
#pragma unroll
    for (int ni = 0; ni < 4; ++ni)
#pragma unroll
      for (int r = 0; r < 4; ++r) {
        int row = m0 + wr * 64 + mi * 16 + (lane >> 4) * 4 + r;
        int col = n0 + wc * 64 + ni * 16 + (lane & 15);
        float v = acc[mi][ni][r];
        if constexpr (std::is_same_v<OutT, unsigned short>)
          C[(size_t)row * N + col] = f2bf(v);
        else
          C[(size_t)row * N + col] = v;
      }
}

// ---------------- MFMA flash attention, causal-paired + double-buffered ----------
// grid: (16 pairs, NH, B). block 256 = 4 waves; wave w owns 16 q-rows.
// Block processes q-tiles {x, 31-x} sequentially => constant 33 KV-tile iters.
// K/V LDS double-buffered; next tile's global loads issued before compute (T14).
__global__ __launch_bounds__(256, 4) void mfma_attn_kernel(
    const unsigned short* __restrict__ Q,    // [B*S][NH*64]
    const unsigned short* __restrict__ KVb,  // [B*S][1024]; K at col kvh*64
    const unsigned short* __restrict__ Vt,   // [(b*8+kvh)*64+d][S]
    unsigned short* __restrict__ O) {        // [B*S][NH*64]
  __shared__ unsigned short Ks[2][64 * 64];
  __shared__ unsigned short Vs[2][64 * 64];
  __shared__ unsigned short Pl[4 * 16 * 64];
  const int head = blockIdx.y, b = blockIdx.z;
  const int kvh = head >> 2;
  const int tid = threadIdx.x;
  const int w = tid >> 6, lane = tid & 63;
  const int c = lane & 15, g = lane >> 4;
  unsigned short* Plw = Pl + w * 1024;
  const int srow = tid >> 3, sslot = tid & 7;

  const unsigned short* Kbase =
      KVb + (size_t)b * S_LEN * 1024 + kvh * HEADD + sslot * 8;
  const unsigned short* Vbase =
      Vt + ((size_t)(b * NKVH + kvh) * HEADD + srow) * S_LEN + sslot * 8;

  const int qts[2] = {(int)blockIdx.x, (S_LEN / 64 - 1) - (int)blockIdx.x};
  int4 kreg[2], vreg[2];
  int cur = 0;

  // prologue: stage tile 0 (phase 0)
#pragma unroll
  for (int i = 0; i < 2; ++i) {
    kreg[i] = *(const int4*)(Kbase + (size_t)(srow + i * 32) * 1024);
    vreg[i] = *(const int4*)(Vbase + (size_t)(i * 32) * S_LEN);
  }
#pragma unroll
  for (int i = 0; i < 2; ++i) {
    int row = srow + i * 32;
    int sw = (sslot ^ (row & 7)) * 8;
    *(int4*)&Ks[0][row * 64 + sw] = kreg[i];
    *(int4*)&Vs[0][row * 64 + sw] = vreg[i];
  }
  __syncthreads();

  for (int ph = 0; ph < 2; ++ph) {
    const int qt = qts[ph];
    bf16x8 qf[2];
    {
      const unsigned short* qp =
          Q + (size_t)(b * S_LEN + qt * 64 + w * 16 + c) * (NHEADS * HEADD) +
          head * HEADD + g * 8;
      qf[0] = *(const bf16x8*)(qp);
      qf[1] = *(const bf16x8*)(qp + 32);
    }
    f32x4 o_acc[4] = {};
    float mstate[4], lstate[4];
#pragma unroll
    for (int r = 0; r < 4; ++r) { mstate[r] = -INFINITY; lstate[r] = 0.f; }

    for (int t = 0; t <= qt; ++t) {
      const int kv0 = t * 64;
      const bool has_next = !(ph == 1 && t == qt);
      if (has_next) {
        const int kv0n = (t < qt) ? kv0 + 64 : 0;
#pragma unroll
        for (int i = 0; i < 2; ++i) {
          kreg[i] = *(const int4*)(Kbase + (size_t)(kv0n + srow + i * 32) * 1024);
          vreg[i] = *(const int4*)(Vbase + (size_t)(i * 32) * S_LEN + kv0n);
        }
      }
      // ---- QK^T: S[16 q][64 kv] per wave ----
      f32x4 s_acc[4] = {};
#pragma unroll
      for (int ks = 0; ks < 2; ++ks)
#pragma unroll
        for (int kn = 0; kn < 4; ++kn) {
          bf16x8 bf = *(const bf16x8*)&Ks[cur][(kn * 16 + c) * 64 +
                                              (((ks * 4 + g) ^ (c & 7)) * 8)];
          s_acc[kn] =
              __builtin_amdgcn_mfma_f32_16x16x32_bf16(qf[ks], bf, s_acc[kn], 0, 0, 0);
        }
      // ---- scale + causal mask ----
      float s[4][4];
#pragma unroll
      for (int kn = 0; kn < 4; ++kn)
#pragma unroll
        for (int r = 0; r < 4; ++r) s[kn][r] = s_acc[kn][r] * ATT_SCALE;
      if (t == qt) {
#pragma unroll
        for (int kn = 0; kn < 4; ++kn)
#pragma unroll
          for (int r = 0; r < 4; ++r)
            if (kv0 + kn * 16 + c > qt * 64 + w * 16 + g * 4 + r) s[kn][r] = -1e30f;
      }
      // ---- online softmax ----
      float mx[4];
#pragma unroll
      for (int r = 0; r < 4; ++r)
        mx[r] = fmaxf(fmaxf(s[0][r], s[1][r]), fmaxf(s[2][r], s[3][r]));
#pragma unroll
      for (int r = 0; r < 4; ++r) {
        mx[r] = fmaxf(mx[r], __shfl_xor(mx[r], 1));
        mx[r] = fmaxf(mx[r], __shfl_xor(mx[r], 2));
        mx[r] = fmaxf(mx[r], __shfl_xor(mx[r], 4));
        mx[r] = fmaxf(mx[r], __shfl_xor(mx[r], 8));
      }
      float alpha[4];
#pragma unroll
      for (int r = 0; r < 4; ++r) {
        float nm = fmaxf(mstate[r], mx[r]);
        alpha[r] = __expf(mstate[r] - nm);
        mstate[r] = nm;
      }
      float rsum[4] = {0.f, 0.f, 0.f, 0.f};
#pragma unroll
      for (int kn = 0; kn < 4; ++kn)
#pragma unroll
        for (int r = 0; r < 4; ++r) {
          float p = __expf(s[kn][r] - mstate[r]);
          unsigned short pb = f2bf(p);
          rsum[r] += bf2f(pb);
          int q = g * 4 + r, k = kn * 16 + c;
          Plw[q * 64 + (k ^ ((q & 7) << 3))] = pb;
        }
#pragma unroll
      for (int r = 0; r < 4; ++r) {
        rsum[r] += __shfl_xor(rsum[r], 1);
        rsum[r] += __shfl_xor(rsum[r], 2);
        rsum[r] += __shfl_xor(rsum[r], 4);
        rsum[r] += __shfl_xor(rsum[r], 8);
        lstate[r] = lstate[r] * alpha[r] + rsum[r];
      }
#pragma unroll
      for (int dn = 0; dn < 4; ++dn)
#pragma unroll
        for (int r = 0; r < 4; ++r) o_acc[dn][r] *= alpha[r];
      // ---- PV: O[16 q][64 d] += P[16][64] @ V^T ----
      bf16x8 af[2];
#pragma unroll
      for (int ks2 = 0; ks2 < 2; ++ks2)
        af[ks2] = *(const bf16x8*)&Plw[c * 64 + ((ks2 * 32 + g * 8) ^ ((c & 7) << 3))];
#pragma unroll
      for (int ks2 = 0; ks2 < 2; ++ks2)
#pragma unroll
        for (int dn = 0; dn < 4; ++dn) {
          bf16x8 vf = *(const bf16x8*)&Vs[cur][(dn * 16 + c) * 64 +
                                              (((ks2 * 4 + g) ^ (c & 7)) * 8)];
          o_acc[dn] =
              __builtin_amdgcn_mfma_f32_16x16x32_bf16(af[ks2], vf, o_acc[dn], 0, 0, 0);
        }
      __syncthreads();  // all waves done reading buf[cur]
      if (has_next) {
#pragma unroll
        for (int i = 0; i < 2; ++i) {
          int row = srow + i * 32;
          int sw = (sslot ^ (row & 7)) * 8;
          *(int4*)&Ks[cur ^ 1][row * 64 + sw] = kreg[i];
          *(int4*)&Vs[cur ^ 1][row * 64 + sw] = vreg[i];
        }
        __syncthreads();  // writes visible
        cur ^= 1;
      }
    }
    // ---- epilogue for this phase ----
    float inv[4];
#pragma unroll
    for (int r = 0; r < 4; ++r) inv[r] = 1.0f / lstate[r];
#pragma unroll
    for (int dn = 0; dn < 4; ++dn)
#pragma unroll
      for (int r = 0; r < 4; ++r) {
        int row = qt * 64 + w * 16 + g * 4 + r;
        int col = head * HEADD + dn * 16 + c;
        O[(size_t)(b * S_LEN + row) * (NHEADS * HEADD) + col] =
            f2bf(o_acc[dn][r] * inv[r]);
      }
  }
}

extern "C" void kernel_launch(void* const* d_in, const int* in_sizes, int n_in,
                              void* d_out, int out_size, void* d_ws, size_t ws_size,
                              hipStream_t stream) {
  const float* hs = (const float*)d_in[0];
  // d_in[1] = attention_mask: guaranteed causal; implemented analytically
  const float* wq = (const float*)d_in[2];
  const float* wk = (const float*)d_in[3];
  const float* wv = (const float*)d_in[4];
  const float* wo = (const float*)d_in[5];
  float* out = (float*)d_out;

  char* ws = (char*)d_ws;
  unsigned short* hs_bf = (unsigned short*)(ws);                        // 16 MB
  unsigned short* wqT  = (unsigned short*)(ws + ((size_t)16 << 20));    // 8 MB
  unsigned short* wkT  = (unsigned short*)(ws + ((size_t)24 << 20));    // 2 MB (K rows)
  unsigned short* wvT  = (unsigned short*)(ws + ((size_t)26 << 20));    // 2 MB (V rows, contiguous after wkT)
  unsigned short* woT  = (unsigned short*)(ws + ((size_t)28 << 20));    // 8 MB
  unsigned short* Qb   = (unsigned short*)(ws + ((size_t)36 << 20));    // 16 MB
  unsigned short* KVb  = (unsigned short*)(ws + ((size_t)52 << 20));    // 8 MB
  unsigned short* Ab   = (unsigned short*)(ws + ((size_t)60 << 20));    // 16 MB
  unsigned short* VtB  = (unsigned short*)(ws + ((size_t)76 << 20));    // 4 MB

  // 1. hs -> bf16
  int n4 = (B_SZ * S_LEN * HID) / 4;
  cvt_bf16_kernel<<<n4 / 256, 256, 0, stream>>>((const float4*)hs, (ushort4*)hs_bf, n4);

  // 2. weight transposes ([K][N] f32 -> [N][K] bf16)
  dim3 tb(32, 8);
  transpose_cvt_kernel<<<dim3(64, 64), tb, 0, stream>>>(wq, wqT, HID, NHEADS * HEADD);
  transpose_cvt_kernel<<<dim3(16, 64), tb, 0, stream>>>(wk, wkT, HID, NKVH * HEADD);
  transpose_cvt_kernel<<<dim3(16, 64), tb, 0, stream>>>(wv, wvT, HID, NKVH * HEADD);
  transpose_cvt_kernel<<<dim3(64, 64), tb, 0, stream>>>(wo, woT, NHEADS * HEADD, HID);

  // 3. projections: Q (N=2048) and merged KV (N=1024; wkT||wvT contiguous)
  gemm_bt_kernel<unsigned short><<<dim3(16, 32), 256, 0, stream>>>(
      hs_bf, wqT, Qb, B_SZ * S_LEN, NHEADS * HEADD, HID);
  gemm_bt_kernel<unsigned short><<<dim3(8, 32), 256, 0, stream>>>(
      hs_bf, wkT, KVb, B_SZ * S_LEN, 1024, HID);

  // 3b. V -> V^T
  transpose_v_kernel<<<dim3(S_LEN / 32, HEADD / 32, B_SZ * NKVH), tb, 0, stream>>>(
      KVb, VtB);

  // 4. attention (MFMA flash, paired + double-buffered)
  mfma_attn_kernel<<<dim3(S_LEN / 128, NHEADS, B_SZ), 256, 0, stream>>>(
      Qb, KVb, VtB, Ab);

  // 5. output projection (fp32 out)
  gemm_bt_kernel<float><<<dim3(16, 32), 256, 0, stream>>>(
      Ab, woT, out, B_SZ * S_LEN, HID, HID);
}